// Round 5
// baseline (66.016 us; speedup 1.0000x reference)
//
#include <hip/hip_runtime.h>
#include <math.h>

// Clip parameter interval of a segment (start (x0,z0), direction d with
// precomputed 1/dx, 1/dz) against the AABB slab |x|<=hx, |z|<=hz.
// Returns max(t_hi - t_lo, 0) over [0,1]. rcp(0)=inf flows through
// IEEE minNum/maxNum semantics of v_min/v_max correctly.
static __device__ __forceinline__ float slab_dt(
    float x0, float z0, float ivx, float ivz, float hx, float hz)
{
    float t1 = (-hx - x0) * ivx;
    float t2 = ( hx - x0) * ivx;
    float t3 = (-hz - z0) * ivz;
    float t4 = ( hz - z0) * ivz;
    float nx = fminf(t1, t2), fx = fmaxf(t1, t2);
    float nz = fminf(t3, t4), fz = fmaxf(t3, t4);
    float tlo = fmaxf(fmaxf(nx, nz), 0.0f);   // v_max3
    float thi = fminf(fminf(fx, fz), 1.0f);   // v_min3
    return fmaxf(thi - tlo, 0.0f);
}

static __device__ __forceinline__ float rcpf(float x) {
    return __builtin_amdgcn_rcpf(x);
}

#define BLK 256
#define REC 7
#define FPB (BLK * REC)          // 1792 floats per block per input
#define F4PB (FPB / 4)           // 448 float4 per block per input

__global__ __launch_bounds__(BLK) void iou3d_kernel(
    const float* __restrict__ pred,
    const float* __restrict__ tgt,
    float* __restrict__ out,
    int N)
{
    __shared__ float sA[FPB];
    __shared__ float sB[FPB];

    int t = threadIdx.x;
    long fbase = (long)blockIdx.x * FPB;
    long n_floats = (long)N * REC;

    if (fbase + FPB <= n_floats) {
        // full block: coalesced float4 staging (448 f4 per input; FPB%4==0
        // guaranteed only when the block is full AND fbase%4==0, which holds
        // since FPB=1792 is divisible by 4)
        const float4* gA = (const float4*)(pred + fbase);
        const float4* gB = (const float4*)(tgt + fbase);
        float4* s4A = (float4*)sA;
        float4* s4B = (float4*)sB;
        s4A[t] = gA[t];
        s4B[t] = gB[t];
        if (t < F4PB - BLK) {                 // 192 extra
            s4A[BLK + t] = gA[BLK + t];
            s4B[BLK + t] = gB[BLK + t];
        }
    } else {
        // ragged tail block: scalar guarded loads
        int i = blockIdx.x * BLK + t;
        #pragma unroll
        for (int k = 0; k < REC; k++) {
            sA[t * REC + k] = (i < N) ? pred[(long)i * REC + k] : 0.0f;
            sB[t * REC + k] = (i < N) ? tgt[(long)i * REC + k]  : 0.0f;
        }
    }
    __syncthreads();

    int i = blockIdx.x * BLK + t;
    if (i >= N) return;

    // LDS reads: address t*7+k -> stride-7 mod 32 banks = 2 lanes/bank (free)
    const float* la = sA + t * REC;
    const float* lb = sB + t * REC;
    float a_x  = la[0], a_y = la[1], a_z = la[2];
    float a_dx = la[3], a_dy = la[4], a_dz = la[5], a_ry = la[6];
    float b_x  = lb[0], b_y = lb[1], b_z = lb[2];
    float b_dx = lb[3], b_dy = lb[4], b_dz = lb[5], b_ry = lb[6];

    // height overlap (reference: y axis negated, clip at 0)
    float min_h_a = -(a_y + a_dy * 0.5f);
    float max_h_a = -(a_y - a_dy * 0.5f);
    float min_h_b = -(b_y + b_dy * 0.5f);
    float max_h_b = -(b_y - b_dy * 0.5f);
    float h_ov = fmaxf(fminf(max_h_a, max_h_b) - fmaxf(min_h_a, min_h_b), 0.0f);

    // reference quirk: h_a0 is box 0's pred height for ALL rows (uniform,
    // compiles to s_load)
    float y0 = pred[1], dy0 = pred[4];
    float h_a0 = (-(y0 - dy0 * 0.5f)) - (-(y0 + dy0 * 0.5f));

    // ---- A-local frame: A = AABB [-p,p]x[-q,q]; B rotated by theta=rb-ra ----
    float ca = __cosf(a_ry), sa = __sinf(a_ry);
    float cb = __cosf(b_ry), sb = __sinf(b_ry);
    float c  = cb * ca + sb * sa;     // cos(rb - ra)
    float sn = sb * ca - cb * sa;     // sin(rb - ra)
    float exw = b_x - a_x, ezw = b_z - a_z;
    float ox =  ca * exw + sa * ezw;  // R(-ra) * (cB - cA)
    float oz = -sa * exw + ca * ezw;

    float p = 0.5f * a_dx, q = 0.5f * a_dz;
    float r = 0.5f * b_dx, s = 0.5f * b_dz;

    // B axes scaled by half-extents: r*u, s*w (u=(c,sn), w=R90*u=(-sn,c))
    float ux = r * c,   uz = r * sn;
    float wx = -s * sn, wz = s * c;

    // B corners in A frame, CCW
    float B0x = ox + ux + wx, B0z = oz + uz + wz;
    float B1x = ox - ux + wx, B1z = oz - uz + wz;
    float B2x = ox - ux - wx, B2z = oz - uz - wz;
    float B3x = ox + ux - wx, B3z = oz + uz - wz;

    // ---- Part 1: B's edges clipped to A (AABB slabs) ----
    float i_ux = rcpf(ux), i_uz = rcpf(uz);
    float i_wx = rcpf(wx), i_wz = rcpf(wz);

    float dt0 = slab_dt(B0x, B0z, -0.5f * i_ux, -0.5f * i_uz, p, q);
    float dt1 = slab_dt(B1x, B1z, -0.5f * i_wx, -0.5f * i_wz, p, q);
    float dt2 = slab_dt(B2x, B2z,  0.5f * i_ux,  0.5f * i_uz, p, q);
    float dt3 = slab_dt(B3x, B3z,  0.5f * i_wx,  0.5f * i_wz, p, q);

    // Green contributions in closed form (D1=cross(o,u), D2=dot(o,u))
    float D1 = ox * sn - oz * c;
    float D2 = ox * c + oz * sn;
    float rs = r * s;
    float part1 = 2.0f * (rs * (dt0 + dt1 + dt2 + dt3)
                        + r * D1 * (dt2 - dt0)
                        + s * D2 * (dt3 - dt1));

    // ---- Part 2: A's edges clipped to B (slab clip in B's (u,w) coords) ----
    float Pc = p * c, Psn = p * sn, Qc = q * c, Qsn = q * sn;
    float i_Pc = rcpf(Pc), i_Psn = rcpf(Psn);
    float i_Qc = rcpf(Qc), i_Qsn = rcpf(Qsn);

    float fu0 =  Pc + Qsn - D2, fw0 = -Psn + Qc + D1;  // A0=( p, q)
    float fu1 = -Pc + Qsn - D2, fw1 =  Psn + Qc + D1;  // A1=(-p, q)
    float fu2 = -Pc - Qsn - D2, fw2 =  Psn - Qc + D1;  // A2=(-p,-q)
    float fu3 =  Pc - Qsn - D2, fw3 = -Psn - Qc + D1;  // A3=( p,-q)

    float dA0 = slab_dt(fu0, fw0, -0.5f * i_Pc,   0.5f * i_Psn, r, s);
    float dA1 = slab_dt(fu1, fw1, -0.5f * i_Qsn, -0.5f * i_Qc,  r, s);
    float dA2 = slab_dt(fu2, fw2,  0.5f * i_Pc,  -0.5f * i_Psn, r, s);
    float dA3 = slab_dt(fu3, fw3,  0.5f * i_Qsn,  0.5f * i_Qc,  r, s);

    float part2 = 2.0f * p * q * (dA0 + dA1 + dA2 + dA3);

    float area = 0.5f * fabsf(part1 + part2);

    float area_a = a_dx * a_dz;
    float area_b = b_dx * b_dz;

    float overlap3d = area * h_ov;
    float union3d = area_a * h_a0 + area_b * (max_h_b - min_h_b) - overlap3d;
    out[i] = __fdividef(overlap3d, union3d);
}

extern "C" void kernel_launch(void* const* d_in, const int* in_sizes, int n_in,
                              void* d_out, int out_size, void* d_ws, size_t ws_size,
                              hipStream_t stream) {
    const float* pred = (const float*)d_in[0];
    const float* tgt  = (const float*)d_in[1];
    float* out = (float*)d_out;
    int N = in_sizes[0] / 7;
    int grid = (N + BLK - 1) / BLK;
    hipLaunchKernelGGL(iou3d_kernel, dim3(grid), dim3(BLK), 0, stream,
                       pred, tgt, out, N);
}

// Round 6
// 64.647 us; speedup vs baseline: 1.0212x; 1.0212x over previous
//
#include <hip/hip_runtime.h>
#include <math.h>

// Clip parameter interval of a segment (start (x0,z0), direction d with
// precomputed 1/dx, 1/dz) against the AABB slab |x|<=hx, |z|<=hz.
// Returns max(t_hi - t_lo, 0) over [0,1]. rcp(0)=inf flows through
// IEEE minNum/maxNum semantics of v_min/v_max correctly.
static __device__ __forceinline__ float slab_dt(
    float x0, float z0, float ivx, float ivz, float hx, float hz)
{
    float t1 = (-hx - x0) * ivx;
    float t2 = ( hx - x0) * ivx;
    float t3 = (-hz - z0) * ivz;
    float t4 = ( hz - z0) * ivz;
    float nx = fminf(t1, t2), fx = fmaxf(t1, t2);
    float nz = fminf(t3, t4), fz = fmaxf(t3, t4);
    float tlo = fmaxf(fmaxf(nx, nz), 0.0f);   // v_max3
    float thi = fminf(fminf(fx, fz), 1.0f);   // v_min3
    return fmaxf(thi - tlo, 0.0f);
}

static __device__ __forceinline__ float rcpf(float x) {
    return __builtin_amdgcn_rcpf(x);
}

#define BLK 1024   // 4x fewer workgroups than round 4/5; residency unchanged
                   // (1 wg/CU x 16 waves = 4 waves/SIMD, VGPR ~52 << 64 cap)

__global__ __launch_bounds__(BLK) void iou3d_kernel(
    const float* __restrict__ pred,
    const float* __restrict__ tgt,
    float* __restrict__ out,
    int N)
{
    int i = blockIdx.x * BLK + threadIdx.x;
    if (i >= N) return;

    const float* pa = pred + (long)i * 7;
    const float* pb = tgt  + (long)i * 7;

    float a_x  = pa[0], a_y = pa[1], a_z = pa[2];
    float a_dx = pa[3], a_dy = pa[4], a_dz = pa[5], a_ry = pa[6];
    float b_x  = pb[0], b_y = pb[1], b_z = pb[2];
    float b_dx = pb[3], b_dy = pb[4], b_dz = pb[5], b_ry = pb[6];

    // height overlap (reference: y axis negated, clip at 0)
    float min_h_a = -(a_y + a_dy * 0.5f);
    float max_h_a = -(a_y - a_dy * 0.5f);
    float min_h_b = -(b_y + b_dy * 0.5f);
    float max_h_b = -(b_y - b_dy * 0.5f);
    float h_ov = fmaxf(fminf(max_h_a, max_h_b) - fmaxf(min_h_a, min_h_b), 0.0f);

    // reference quirk: h_a0 is box 0's pred height for ALL rows (uniform)
    float y0 = pred[1], dy0 = pred[4];
    float h_a0 = (-(y0 - dy0 * 0.5f)) - (-(y0 + dy0 * 0.5f));

    // ---- A-local frame: A = AABB [-p,p]x[-q,q]; B rotated by theta=rb-ra ----
    float ca = __cosf(a_ry), sa = __sinf(a_ry);
    float cb = __cosf(b_ry), sb = __sinf(b_ry);
    float c  = cb * ca + sb * sa;     // cos(rb - ra)
    float sn = sb * ca - cb * sa;     // sin(rb - ra)
    float exw = b_x - a_x, ezw = b_z - a_z;
    float ox =  ca * exw + sa * ezw;  // R(-ra) * (cB - cA)
    float oz = -sa * exw + ca * ezw;

    float p = 0.5f * a_dx, q = 0.5f * a_dz;
    float r = 0.5f * b_dx, s = 0.5f * b_dz;

    // B axes scaled by half-extents: r*u, s*w (u=(c,sn), w=R90*u=(-sn,c))
    float ux = r * c,   uz = r * sn;
    float wx = -s * sn, wz = s * c;

    // B corners in A frame, CCW
    float B0x = ox + ux + wx, B0z = oz + uz + wz;
    float B1x = ox - ux + wx, B1z = oz - uz + wz;
    float B2x = ox - ux - wx, B2z = oz - uz - wz;
    float B3x = ox + ux - wx, B3z = oz + uz - wz;

    // ---- Part 1: B's edges clipped to A (AABB slabs) ----
    float i_ux = rcpf(ux), i_uz = rcpf(uz);
    float i_wx = rcpf(wx), i_wz = rcpf(wz);

    float dt0 = slab_dt(B0x, B0z, -0.5f * i_ux, -0.5f * i_uz, p, q);
    float dt1 = slab_dt(B1x, B1z, -0.5f * i_wx, -0.5f * i_wz, p, q);
    float dt2 = slab_dt(B2x, B2z,  0.5f * i_ux,  0.5f * i_uz, p, q);
    float dt3 = slab_dt(B3x, B3z,  0.5f * i_wx,  0.5f * i_wz, p, q);

    // Green contributions in closed form (D1=cross(o,u), D2=dot(o,u))
    float D1 = ox * sn - oz * c;
    float D2 = ox * c + oz * sn;
    float rs = r * s;
    float part1 = 2.0f * (rs * (dt0 + dt1 + dt2 + dt3)
                        + r * D1 * (dt2 - dt0)
                        + s * D2 * (dt3 - dt1));

    // ---- Part 2: A's edges clipped to B (slab clip in B's (u,w) coords) ----
    float Pc = p * c, Psn = p * sn, Qc = q * c, Qsn = q * sn;
    float i_Pc = rcpf(Pc), i_Psn = rcpf(Psn);
    float i_Qc = rcpf(Qc), i_Qsn = rcpf(Qsn);

    float fu0 =  Pc + Qsn - D2, fw0 = -Psn + Qc + D1;  // A0=( p, q)
    float fu1 = -Pc + Qsn - D2, fw1 =  Psn + Qc + D1;  // A1=(-p, q)
    float fu2 = -Pc - Qsn - D2, fw2 =  Psn - Qc + D1;  // A2=(-p,-q)
    float fu3 =  Pc - Qsn - D2, fw3 = -Psn - Qc + D1;  // A3=( p,-q)

    float dA0 = slab_dt(fu0, fw0, -0.5f * i_Pc,   0.5f * i_Psn, r, s);
    float dA1 = slab_dt(fu1, fw1, -0.5f * i_Qsn, -0.5f * i_Qc,  r, s);
    float dA2 = slab_dt(fu2, fw2,  0.5f * i_Pc,  -0.5f * i_Psn, r, s);
    float dA3 = slab_dt(fu3, fw3,  0.5f * i_Qsn,  0.5f * i_Qc,  r, s);

    float part2 = 2.0f * p * q * (dA0 + dA1 + dA2 + dA3);

    float area = 0.5f * fabsf(part1 + part2);

    float area_a = a_dx * a_dz;
    float area_b = b_dx * b_dz;

    float overlap3d = area * h_ov;
    float union3d = area_a * h_a0 + area_b * (max_h_b - min_h_b) - overlap3d;
    out[i] = __fdividef(overlap3d, union3d);
}

extern "C" void kernel_launch(void* const* d_in, const int* in_sizes, int n_in,
                              void* d_out, int out_size, void* d_ws, size_t ws_size,
                              hipStream_t stream) {
    const float* pred = (const float*)d_in[0];
    const float* tgt  = (const float*)d_in[1];
    float* out = (float*)d_out;
    int N = in_sizes[0] / 7;
    int grid = (N + BLK - 1) / BLK;
    hipLaunchKernelGGL(iou3d_kernel, dim3(grid), dim3(BLK), 0, stream,
                       pred, tgt, out, N);
}